// Round 2
// baseline (297.316 us; speedup 1.0000x reference)
//
#include <hip/hip_runtime.h>

#define C_IN   64
#define C_OUT  128
#define Himg   128
#define Wimg   128
#define TROWS  8
#define TCOLS  32
#define HROWS  10   // TROWS+2
#define HCOLS  34   // TCOLS+2

typedef __bf16 bf16x8 __attribute__((ext_vector_type(8)));
typedef float  f32x4  __attribute__((ext_vector_type(4)));

__device__ __forceinline__ unsigned int pack2(float a, float b) {
  union { __bf16 h; unsigned short s; } ua, ub;
  ua.h = (__bf16)a; ub.h = (__bf16)b;
  return (unsigned int)ua.s | ((unsigned int)ub.s << 16);
}

// fp32 W[co][c][ky][kx] -> bf16 Wt[tap][co][c]
__global__ void wt_transform(const float* __restrict__ w, unsigned short* __restrict__ wt) {
  const int idx = blockIdx.x * 256 + threadIdx.x;
  if (idx >= 9 * C_OUT * C_IN) return;
  const int c   = idx & (C_IN - 1);
  const int co  = (idx >> 6) & (C_OUT - 1);
  const int tap = idx >> 13;
  const int ky = tap / 3, kx = tap % 3;
  const float f = w[((co * C_IN + c) * 3 + ky) * 3 + kx];
  union { __bf16 h; unsigned short s; } u; u.h = (__bf16)f;
  wt[idx] = u.s;
}

__global__ __launch_bounds__(256, 3)
void conv_mfma(const float* __restrict__ xin, const unsigned short* __restrict__ wt,
               const float* __restrict__ bias, float* __restrict__ out) {
  // X tile only: rows (r*HCOLS + x), each 64 ch * 2B = 128 B, XOR-swizzled by (row&7)<<4
  __shared__ __align__(16) unsigned char Xs[HROWS * HCOLS * C_IN * 2];   // 43520 B

  const int tid = threadIdx.x;
  // bijective XCD swizzle: 2304 blocks = 8 XCDs * 288; contiguous logical range per XCD
  const int wg  = (blockIdx.x & 7) * 288 + (blockIdx.x >> 3);
  const int bx  = wg & 3;
  const int by  = (wg >> 2) & 15;
  const int img = wg >> 6;
  const int gy0 = by * TROWS;
  const int gx0 = bx * TCOLS;

  // ---- stage X tile interior (fp32 -> bf16), storage cols 1..32 ----
  {
    const int xi = tid & 31;        // x offset within tile
    const int cq = tid >> 5;        // 0..7 -> 4 channels each
    #pragma unroll
    for (int pass = 0; pass < 2; ++pass) {
      const int c0 = pass * 32 + cq * 4;
      const float* pbase = xin + ((size_t)img * C_IN + c0) * (Himg * Wimg) + gx0 + xi;
      #pragma unroll
      for (int r = 0; r < HROWS; ++r) {
        const int gy = gy0 - 1 + r;
        float f0 = 0.f, f1 = 0.f, f2 = 0.f, f3 = 0.f;
        if (gy >= 0 && gy < Himg) {
          const float* p = pbase + (size_t)gy * Wimg;
          f0 = p[0];
          f1 = p[Himg * Wimg];
          f2 = p[2 * Himg * Wimg];
          f3 = p[3 * Himg * Wimg];
        }
        const int row = r * HCOLS + 1 + xi;
        const int off = (2 * c0) ^ ((row & 7) << 4);
        *(uint2*)(&Xs[row * 128 + off]) = make_uint2(pack2(f0, f1), pack2(f2, f3));
      }
    }
  }
  // ---- halo columns (storage col 0 and 33) ----
  for (int idx = tid; idx < 2 * HROWS * C_IN; idx += 256) {
    const int side = (idx >= HROWS * C_IN) ? 1 : 0;
    const int rem  = idx - side * HROWS * C_IN;
    const int c = rem & (C_IN - 1);
    const int r = rem >> 6;
    const int gy = gy0 - 1 + r;
    const int gx = side ? (gx0 + TCOLS) : (gx0 - 1);
    float f = 0.f;
    if (gy >= 0 && gy < Himg && gx >= 0 && gx < Wimg)
      f = xin[((size_t)img * C_IN + c) * (Himg * Wimg) + (size_t)gy * Wimg + gx];
    const int row = r * HCOLS + (side ? (HCOLS - 1) : 0);
    const int off = (2 * c) ^ ((row & 7) << 4);
    union { __bf16 h; unsigned short s; } u; u.h = (__bf16)f;
    *(unsigned short*)(&Xs[row * 128 + off]) = u.s;
  }

  const int lane = tid & 63;
  const int wv   = tid >> 6;     // wave 0..3 -> pixel strip
  const int l15  = lane & 15;
  const int lq   = lane >> 4;

  f32x4 acc[8][4];
  #pragma unroll
  for (int mf = 0; mf < 8; ++mf)
    #pragma unroll
    for (int nf = 0; nf < 4; ++nf)
      acc[mf][nf] = f32x4{0.f, 0.f, 0.f, 0.f};

  int bpy[4], bpx[4];
  #pragma unroll
  for (int nf = 0; nf < 4; ++nf) {
    const int pxl = wv * 64 + nf * 16 + l15;
    bpy[nf] = pxl >> 5;
    bpx[nf] = pxl & 31;
  }

  // A-fragment base in global wt: lane reads wt[tap][mf*16+l15][ks*32 + lq*8 .. +7]
  const unsigned short* wbase = wt + l15 * C_IN + lq * 8;

  __syncthreads();   // single barrier: Xs ready, read-only hereafter

  for (int t = 0; t < 9; ++t) {
    const int dy = t / 3, dx = t - dy * 3;
    const unsigned short* wtap = wbase + (size_t)t * (C_OUT * C_IN);
    int boff[4];
    #pragma unroll
    for (int nf = 0; nf < 4; ++nf) {
      const int row = (bpy[nf] + dy) * HCOLS + (bpx[nf] + dx);
      boff[nf] = row * 128 + ((lq * 16) ^ ((row & 7) << 4));
    }
    #pragma unroll
    for (int ks = 0; ks < 2; ++ks) {
      bf16x8 b[4];
      #pragma unroll
      for (int nf = 0; nf < 4; ++nf)
        b[nf] = *(const bf16x8*)(&Xs[boff[nf] ^ (ks << 6)]);
      #pragma unroll
      for (int mh = 0; mh < 2; ++mh) {   // mf in halves to cap live registers
        bf16x8 a[4];
        #pragma unroll
        for (int i = 0; i < 4; ++i)
          a[i] = *(const bf16x8*)(wtap + ((mh * 4 + i) * 16) * C_IN + ks * 32);
        #pragma unroll
        for (int i = 0; i < 4; ++i)
          #pragma unroll
          for (int nf = 0; nf < 4; ++nf)
            acc[mh * 4 + i][nf] = __builtin_amdgcn_mfma_f32_16x16x32_bf16(a[i], b[nf], acc[mh * 4 + i][nf], 0, 0, 0);
      }
    }
  }

  // ---- epilogue: bias + fp32 store ----
  float4 bld[8];
  #pragma unroll
  for (int mf = 0; mf < 8; ++mf)
    bld[mf] = *(const float4*)(bias + mf * 16 + lq * 4);

  #pragma unroll
  for (int nf = 0; nf < 4; ++nf) {
    const int py = bpy[nf], px = bpx[nf];
    float* op = out + (size_t)img * C_OUT * (Himg * Wimg) + (size_t)(gy0 + py) * Wimg + gx0 + px;
    #pragma unroll
    for (int mf = 0; mf < 8; ++mf) {
      #pragma unroll
      for (int i = 0; i < 4; ++i) {
        const int co = mf * 16 + lq * 4 + i;
        op[(size_t)co * (Himg * Wimg)] = acc[mf][nf][i] + (&bld[mf].x)[i];
      }
    }
  }
}

extern "C" void kernel_launch(void* const* d_in, const int* in_sizes, int n_in,
                              void* d_out, int out_size, void* d_ws, size_t ws_size,
                              hipStream_t stream) {
  const float* x    = (const float*)d_in[0];
  const float* w    = (const float*)d_in[1];
  const float* bias = (const float*)d_in[2];
  float* out = (float*)d_out;
  unsigned short* wt = (unsigned short*)d_ws;  // 9*128*64 bf16 = 144 KB

  wt_transform<<<(9 * C_OUT * C_IN + 255) / 256, 256, 0, stream>>>(w, wt);

  conv_mfma<<<dim3(2304), 256, 0, stream>>>(x, wt, bias, out);
}

// Round 3
// 259.528 us; speedup vs baseline: 1.1456x; 1.1456x over previous
//
#include <hip/hip_runtime.h>

#define C_IN   64
#define C_OUT  128
#define Himg   128
#define Wimg   128
#define HW     (Himg * Wimg)
#define TROWS  8
#define TCOLS  32
#define HROWS  10   // TROWS+2
#define HCOLS  34   // TCOLS+2

typedef __bf16 bf16x8 __attribute__((ext_vector_type(8)));
typedef float  f32x16 __attribute__((ext_vector_type(16)));

__device__ __forceinline__ unsigned int pack2(float a, float b) {
  union { __bf16 h; unsigned short s; } ua, ub;
  ua.h = (__bf16)a; ub.h = (__bf16)b;
  return (unsigned int)ua.s | ((unsigned int)ub.s << 16);
}

// fp32 W[co][c][ky][kx] -> bf16 Wt[tap][co][c]
__global__ void wt_transform(const float* __restrict__ w, unsigned short* __restrict__ wt) {
  const int idx = blockIdx.x * 256 + threadIdx.x;
  if (idx >= 9 * C_OUT * C_IN) return;
  const int c   = idx & (C_IN - 1);
  const int co  = (idx >> 6) & (C_OUT - 1);
  const int tap = idx >> 13;
  const int ky = tap / 3, kx = tap % 3;
  const float f = w[((co * C_IN + c) * 3 + ky) * 3 + kx];
  union { __bf16 h; unsigned short s; } u; u.h = (__bf16)f;
  wt[idx] = u.s;
}

// Load one K-half (K=32, two ks-steps of 16): 8 A-frags (global) + 4 B-frags (LDS)
#define LOAD_HALF(AA, BB, T, H)                                                     \
  {                                                                                 \
    const int dy_ = (T) >= 6 ? 2 : ((T) >= 3 ? 1 : 0);                              \
    const int dx_ = (T) - dy_ * 3;                                                  \
    _Pragma("unroll")                                                               \
    for (int nf_ = 0; nf_ < 2; ++nf_) {                                             \
      const int row_ = (wv * 2 + nf_ + dy_) * HCOLS + dx_ + lpx;                    \
      const int base_ = row_ * 128 + ((((H) << 6) + (lkh << 4)) ^ ((row_ & 7) << 4)); \
      BB[nf_ * 2 + 0] = *(const bf16x8*)(&Xs[base_]);                               \
      BB[nf_ * 2 + 1] = *(const bf16x8*)(&Xs[base_ ^ 32]);                          \
    }                                                                               \
    const unsigned short* wt_ = wl + (size_t)(T) * (C_OUT * C_IN) + (H) * 32;       \
    _Pragma("unroll")                                                               \
    for (int mf_ = 0; mf_ < 4; ++mf_) {                                             \
      AA[mf_ * 2 + 0] = *(const bf16x8*)(wt_ + mf_ * 32 * C_IN);                    \
      AA[mf_ * 2 + 1] = *(const bf16x8*)(wt_ + mf_ * 32 * C_IN + 16);               \
    }                                                                               \
  }

#define MFMA_HALF(AA, BB)                                                           \
  _Pragma("unroll")                                                                 \
  for (int mf_ = 0; mf_ < 4; ++mf_)                                                 \
    _Pragma("unroll")                                                               \
    for (int nf_ = 0; nf_ < 2; ++nf_) {                                             \
      acc[mf_][nf_] = __builtin_amdgcn_mfma_f32_32x32x16_bf16(AA[mf_*2+0], BB[nf_*2+0], acc[mf_][nf_], 0, 0, 0); \
      acc[mf_][nf_] = __builtin_amdgcn_mfma_f32_32x32x16_bf16(AA[mf_*2+1], BB[nf_*2+1], acc[mf_][nf_], 0, 0, 0); \
    }

__global__ __launch_bounds__(256, 2)
void conv_mfma(const float* __restrict__ xin, const unsigned short* __restrict__ wt,
               const float* __restrict__ bias, float* __restrict__ out) {
  // X tile: rows (r*HCOLS + x), each 64 ch * 2B = 128 B, XOR-swizzled by (row&7)<<4
  __shared__ __align__(16) unsigned char Xs[HROWS * HCOLS * C_IN * 2];   // 43520 B

  const int tid = threadIdx.x;
  // bijective XCD swizzle: 2304 blocks = 8 XCDs * 288
  const int wg  = (blockIdx.x & 7) * 288 + (blockIdx.x >> 3);
  const int bx  = wg & 3;
  const int by  = (wg >> 2) & 15;
  const int img = wg >> 6;
  const int gy0 = by * TROWS;
  const int gx0 = bx * TCOLS;

  // ---- stage X tile interior (fp32 -> bf16), storage cols 1..32 ----
  {
    const int xi = tid & 31;
    const int cq = tid >> 5;
    #pragma unroll
    for (int pass = 0; pass < 2; ++pass) {
      const int c0 = pass * 32 + cq * 4;
      const float* pbase = xin + ((size_t)img * C_IN + c0) * HW + gx0 + xi;
      #pragma unroll
      for (int r = 0; r < HROWS; ++r) {
        const int gy = gy0 - 1 + r;
        float f0 = 0.f, f1 = 0.f, f2 = 0.f, f3 = 0.f;
        if (gy >= 0 && gy < Himg) {
          const float* p = pbase + (size_t)gy * Wimg;
          f0 = p[0];
          f1 = p[HW];
          f2 = p[2 * HW];
          f3 = p[3 * HW];
        }
        const int row = r * HCOLS + 1 + xi;
        const int off = (2 * c0) ^ ((row & 7) << 4);
        *(uint2*)(&Xs[row * 128 + off]) = make_uint2(pack2(f0, f1), pack2(f2, f3));
      }
    }
  }
  // ---- halo columns (storage col 0 and 33) ----
  for (int idx = tid; idx < 2 * HROWS * C_IN; idx += 256) {
    const int side = (idx >= HROWS * C_IN) ? 1 : 0;
    const int rem  = idx - side * HROWS * C_IN;
    const int c = rem & (C_IN - 1);
    const int r = rem >> 6;
    const int gy = gy0 - 1 + r;
    const int gx = side ? (gx0 + TCOLS) : (gx0 - 1);
    float f = 0.f;
    if (gy >= 0 && gy < Himg && gx >= 0 && gx < Wimg)
      f = xin[((size_t)img * C_IN + c) * HW + (size_t)gy * Wimg + gx];
    const int row = r * HCOLS + (side ? (HCOLS - 1) : 0);
    const int off = (2 * c) ^ ((row & 7) << 4);
    union { __bf16 h; unsigned short s; } u; u.h = (__bf16)f;
    *(unsigned short*)(&Xs[row * 128 + off]) = u.s;
  }

  const int lane = tid & 63;
  const int wv   = tid >> 6;     // wave -> 64-px strip (2 rows of 32)
  const int lpx  = lane & 31;    // pixel column within 32
  const int lkh  = lane >> 5;    // k-half (channels) for A/B frags

  f32x16 acc[4][2];
  #pragma unroll
  for (int mf = 0; mf < 4; ++mf)
    #pragma unroll
    for (int nf = 0; nf < 2; ++nf)
      acc[mf][nf] = (f32x16)(0.f);

  // A-frag lane base: wt[tap][mf*32 + lpx][ks*16 + lkh*8 ...+7]
  const unsigned short* wl = wt + lpx * C_IN + lkh * 8;

  __syncthreads();   // Xs ready; read-only hereafter

  bf16x8 aA[8], bA[4], aB[8], bB[4];
  LOAD_HALF(aA, bA, 0, 0)
  for (int t = 0; t < 9; ++t) {
    LOAD_HALF(aB, bB, t, 1)          // prefetch second K-half of tap t
    MFMA_HALF(aA, bA)
    if (t < 8) LOAD_HALF(aA, bA, t + 1, 0)   // prefetch first K-half of tap t+1
    MFMA_HALF(aB, bB)
  }

  // ---- epilogue: bias + fp32 full-line stores ----
  float4 bq[4][4];   // [mf][r>>2]
  #pragma unroll
  for (int mf = 0; mf < 4; ++mf)
    #pragma unroll
    for (int rq = 0; rq < 4; ++rq)
      bq[mf][rq] = *(const float4*)(bias + mf * 32 + rq * 8 + lkh * 4);

  #pragma unroll
  for (int nf = 0; nf < 2; ++nf) {
    const int py = wv * 2 + nf;
    float* op = out + (size_t)img * C_OUT * HW + (size_t)(gy0 + py) * Wimg + gx0 + lpx;
    #pragma unroll
    for (int mf = 0; mf < 4; ++mf) {
      #pragma unroll
      for (int r = 0; r < 16; ++r) {
        const int co = mf * 32 + (r & 3) + 8 * (r >> 2) + lkh * 4;
        op[(size_t)co * HW] = acc[mf][nf][r] + ((const float*)&bq[mf][r >> 2])[r & 3];
      }
    }
  }
}

extern "C" void kernel_launch(void* const* d_in, const int* in_sizes, int n_in,
                              void* d_out, int out_size, void* d_ws, size_t ws_size,
                              hipStream_t stream) {
  const float* x    = (const float*)d_in[0];
  const float* w    = (const float*)d_in[1];
  const float* bias = (const float*)d_in[2];
  float* out = (float*)d_out;
  unsigned short* wt = (unsigned short*)d_ws;  // 9*128*64 bf16 = 144 KB

  wt_transform<<<(9 * C_OUT * C_IN + 255) / 256, 256, 0, stream>>>(w, wt);

  conv_mfma<<<dim3(2304), 256, 0, stream>>>(x, wt, bias, out);
}

// Round 4
// 165.494 us; speedup vs baseline: 1.7965x; 1.5682x over previous
//
#include <hip/hip_runtime.h>

#define C_IN   64
#define C_OUT  128
#define Himg   128
#define Wimg   128
#define HW     (Himg * Wimg)
#define TROWS  8
#define TCOLS  32
#define HROWS  10   // TROWS+2
#define HCOLS  34   // TCOLS+2
#define WS_TAP 16384

typedef __bf16 bf16x8 __attribute__((ext_vector_type(8)));
typedef float  f32x16 __attribute__((ext_vector_type(16)));

__device__ __forceinline__ unsigned int pack2(float a, float b) {
  union { __bf16 h; unsigned short s; } ua, ub;
  ua.h = (__bf16)a; ub.h = (__bf16)b;
  return (unsigned int)ua.s | ((unsigned int)ub.s << 16);
}

__device__ __forceinline__ void gload_lds16(const void* g, void* l) {
  __builtin_amdgcn_global_load_lds((const __attribute__((address_space(1))) void*)g,
                                   (__attribute__((address_space(3))) void*)l, 16, 0, 0);
}

// fp32 W[co][c][3][3] -> bf16 wt[tap][co][c XOR-swizzled]
// element index = tap*8192 + co*64 + ((2c ^ ((co&7)<<4))>>1), so a LINEAR
// global_load_lds into Ws yields the swizzled LDS layout (rule #21).
__global__ void wt_transform(const float* __restrict__ w, unsigned short* __restrict__ wt) {
  const int idx = blockIdx.x * 256 + threadIdx.x;
  if (idx >= 9 * C_OUT * C_IN) return;
  const int c   = idx & 63;
  const int co  = (idx >> 6) & 127;
  const int tap = idx >> 13;
  const int ky = tap / 3, kx = tap % 3;
  const float f = w[((co * C_IN + c) * 3 + ky) * 3 + kx];
  union { __bf16 h; unsigned short s; } u; u.h = (__bf16)f;
  const int sb = (2 * c) ^ ((co & 7) << 4);
  wt[tap * 8192 + co * 64 + (sb >> 1)] = u.s;
}

__global__ __launch_bounds__(256, 2)
void conv_mfma(const float* __restrict__ xin, const unsigned short* __restrict__ wt,
               const float* __restrict__ bias, float* __restrict__ out) {
  __shared__ __align__(16) unsigned char Xs[HROWS * HCOLS * 128];   // 43520
  __shared__ __align__(16) unsigned char Ws[2][WS_TAP];             // 32768

  const int tid = threadIdx.x;
  // bijective XCD swizzle: 2304 = 8 * 288
  const int wg  = (blockIdx.x & 7) * 288 + (blockIdx.x >> 3);
  const int bx  = wg & 3;
  const int by  = (wg >> 2) & 15;
  const int img = wg >> 6;
  const int gy0 = by * TROWS;
  const int gx0 = bx * TCOLS;
  const int lane = tid & 63;
  const int wv   = tid >> 6;

  // ---- issue async Ws tap-0 staging first; X staging below covers its latency ----
  {
    const unsigned short* s0 = wt + lane * 8;
    #pragma unroll
    for (int j = 0; j < 4; ++j) {
      const int i = wv * 4 + j;
      gload_lds16(s0 + i * 512, &Ws[0][i * 1024]);
    }
  }

  // ---- stage X tile interior (fp32 -> bf16), storage cols 1..32 ----
  {
    const int xi = tid & 31;
    const int cq = tid >> 5;
    #pragma unroll
    for (int pass = 0; pass < 2; ++pass) {
      const int c0 = pass * 32 + cq * 4;
      const float* pbase = xin + ((size_t)img * C_IN + c0) * HW + gx0 + xi;
      #pragma unroll
      for (int r = 0; r < HROWS; ++r) {
        const int gy = gy0 - 1 + r;
        float f0 = 0.f, f1 = 0.f, f2 = 0.f, f3 = 0.f;
        if (gy >= 0 && gy < Himg) {
          const float* p = pbase + (size_t)gy * Wimg;
          f0 = p[0];
          f1 = p[HW];
          f2 = p[2 * HW];
          f3 = p[3 * HW];
        }
        const int row = r * HCOLS + 1 + xi;
        const int off = (2 * c0) ^ ((row & 7) << 4);
        *(uint2*)(&Xs[row * 128 + off]) = make_uint2(pack2(f0, f1), pack2(f2, f3));
      }
    }
  }
  // ---- halo columns (storage col 0 and 33) ----
  for (int idx = tid; idx < 2 * HROWS * C_IN; idx += 256) {
    const int side = (idx >= HROWS * C_IN) ? 1 : 0;
    const int rem  = idx - side * HROWS * C_IN;
    const int c = rem & 63;
    const int r = rem >> 6;
    const int gy = gy0 - 1 + r;
    const int gx = side ? (gx0 + TCOLS) : (gx0 - 1);
    float f = 0.f;
    if (gy >= 0 && gy < Himg && gx >= 0 && gx < Wimg)
      f = xin[((size_t)img * C_IN + c) * HW + (size_t)gy * Wimg + gx];
    const int row = r * HCOLS + (side ? (HCOLS - 1) : 0);
    const int off = (2 * c) ^ ((row & 7) << 4);
    union { __bf16 h; unsigned short s; } u; u.h = (__bf16)f;
    *(unsigned short*)(&Xs[row * 128 + off]) = u.s;
  }

  // wave tile: (wm: co-half 64) x (wn: px-half 4 rows of 32)
  const int lpx = lane & 31;
  const int lkh = lane >> 5;
  const int wm  = wv >> 1;
  const int wn  = wv & 1;

  f32x16 acc[2][4];
  #pragma unroll
  for (int mf = 0; mf < 2; ++mf)
    #pragma unroll
    for (int nf = 0; nf < 4; ++nf)
      acc[mf][nf] = (f32x16)(0.f);

  const int abase = (wm * 64 + lpx) * 128;   // + mf*4096
  const int akey  = (lpx & 7) << 4;          // (co&7)<<4 since wm*64, mf*32 are mult of 8

  __syncthreads();   // Xs + Ws[0] ready (syncthreads drains vmcnt)

  for (int t = 0; t < 9; ++t) {
    if (t < 8) {   // async-prefetch tap t+1; its buffer was last read in tap t-1 (barrier-safe)
      const unsigned short* sn = wt + (t + 1) * 8192 + lane * 8;
      unsigned char* db = Ws[(t + 1) & 1];
      #pragma unroll
      for (int j = 0; j < 4; ++j) {
        const int i = wv * 4 + j;
        gload_lds16(sn + i * 512, &db[i * 1024]);
      }
    }
    const int dy = (t >= 6) ? 2 : (t >= 3 ? 1 : 0);
    const int dx = t - dy * 3;
    const unsigned char* wsb = Ws[t & 1];
    int brow[4], bkey[4];
    #pragma unroll
    for (int nf = 0; nf < 4; ++nf) {
      const int row = (wn * 4 + nf + dy) * HCOLS + dx + lpx;
      brow[nf] = row * 128;
      bkey[nf] = (row & 7) << 4;
    }
    #pragma unroll
    for (int sh = 0; sh < 2; ++sh) {   // k-steps in batches of 2 to bound live regs
      bf16x8 A[2][2], B[4][2];
      #pragma unroll
      for (int ss = 0; ss < 2; ++ss) {
        const int ko = (sh * 2 + ss) * 32 + lkh * 16;
        #pragma unroll
        for (int mf = 0; mf < 2; ++mf)
          A[mf][ss] = *(const bf16x8*)&wsb[abase + mf * 4096 + (ko ^ akey)];
        #pragma unroll
        for (int nf = 0; nf < 4; ++nf)
          B[nf][ss] = *(const bf16x8*)&Xs[brow[nf] + (ko ^ bkey[nf])];
      }
      #pragma unroll
      for (int ss = 0; ss < 2; ++ss)
        #pragma unroll
        for (int mf = 0; mf < 2; ++mf)
          #pragma unroll
          for (int nf = 0; nf < 4; ++nf)
            acc[mf][nf] = __builtin_amdgcn_mfma_f32_32x32x16_bf16(A[mf][ss], B[nf][ss], acc[mf][nf], 0, 0, 0);
    }
    __syncthreads();
  }

  // ---- epilogue: bias + fp32 full-line stores ----
  float4 bq[2][4];
  #pragma unroll
  for (int mf = 0; mf < 2; ++mf)
    #pragma unroll
    for (int rq = 0; rq < 4; ++rq)
      bq[mf][rq] = *(const float4*)(bias + wm * 64 + mf * 32 + rq * 8 + lkh * 4);

  #pragma unroll
  for (int nf = 0; nf < 4; ++nf) {
    const int y = gy0 + wn * 4 + nf;
    float* op = out + (size_t)img * C_OUT * HW + (size_t)y * Wimg + gx0 + lpx;
    #pragma unroll
    for (int mf = 0; mf < 2; ++mf) {
      #pragma unroll
      for (int r = 0; r < 16; ++r) {
        const int co = wm * 64 + mf * 32 + (r & 3) + 8 * (r >> 2) + lkh * 4;
        op[(size_t)co * HW] = acc[mf][nf][r] + ((const float*)&bq[mf][r >> 2])[r & 3];
      }
    }
  }
}

extern "C" void kernel_launch(void* const* d_in, const int* in_sizes, int n_in,
                              void* d_out, int out_size, void* d_ws, size_t ws_size,
                              hipStream_t stream) {
  const float* x    = (const float*)d_in[0];
  const float* w    = (const float*)d_in[1];
  const float* bias = (const float*)d_in[2];
  float* out = (float*)d_out;
  unsigned short* wt = (unsigned short*)d_ws;  // 9*8192 bf16 = 144 KB

  wt_transform<<<(9 * C_OUT * C_IN + 255) / 256, 256, 0, stream>>>(w, wt);

  conv_mfma<<<dim3(2304), 256, 0, stream>>>(x, wt, bias, out);
}

// Round 5
// 161.622 us; speedup vs baseline: 1.8396x; 1.0240x over previous
//
#include <hip/hip_runtime.h>

#define C_IN   64
#define C_OUT  128
#define Himg   128
#define Wimg   128
#define HW     (Himg * Wimg)
#define TROWS  8
#define TCOLS  32
#define HROWS  10   // TROWS+2
#define HCOLS  34   // TCOLS+2
#define XCELLS (HROWS * HCOLS)      // 340 pixel cells per k-group
#define XKSTR  (XCELLS * 16)        // 5440 B: Xs k-group stride
#define WS_TAP 16384

typedef __bf16 bf16x8 __attribute__((ext_vector_type(8)));
typedef float  f32x16 __attribute__((ext_vector_type(16)));

__device__ __forceinline__ unsigned int pack2(float a, float b) {
  union { __bf16 h; unsigned short s; } ua, ub;
  ua.h = (__bf16)a; ub.h = (__bf16)b;
  return (unsigned int)ua.s | ((unsigned int)ub.s << 16);
}

__device__ __forceinline__ void gload_lds16(const void* g, void* l) {
  __builtin_amdgcn_global_load_lds((const __attribute__((address_space(1))) void*)g,
                                   (__attribute__((address_space(3))) void*)l, 16, 0, 0);
}

// fp32 W[co][c][3][3] -> bf16 wt, k-major cells: wt[tap][c>>3][co][c&7]
// so a LINEAR global_load_lds into Ws gives Ws[kidx][co] 16B cells.
__global__ void wt_transform(const float* __restrict__ w, unsigned short* __restrict__ wt) {
  const int idx = blockIdx.x * 256 + threadIdx.x;
  if (idx >= 9 * C_OUT * C_IN) return;
  const int c   = idx & 63;
  const int co  = (idx >> 6) & 127;
  const int tap = idx >> 13;
  const int ky = tap / 3, kx = tap % 3;
  const float f = w[((co * C_IN + c) * 3 + ky) * 3 + kx];
  union { __bf16 h; unsigned short s; } u; u.h = (__bf16)f;
  wt[tap * 8192 + (c >> 3) * 1024 + co * 8 + (c & 7)] = u.s;
}

__global__ __launch_bounds__(256, 2)
void conv_mfma(const float* __restrict__ xin, const unsigned short* __restrict__ wt,
               const float* __restrict__ bias, float* __restrict__ out) {
  __shared__ __align__(16) unsigned char Xs[8 * XKSTR];    // 43520: [kgrp][pixel] 16B cells
  __shared__ __align__(16) unsigned char Ws[2][WS_TAP];    // 32768: [kidx][co] 16B cells

  const int tid = threadIdx.x;
  // bijective XCD swizzle: 2304 = 8 * 288
  const int wg  = (blockIdx.x & 7) * 288 + (blockIdx.x >> 3);
  const int bx  = wg & 3;
  const int by  = (wg >> 2) & 15;
  const int img = wg >> 6;
  const int gy0 = by * TROWS;
  const int gx0 = bx * TCOLS;
  const int lane = tid & 63;
  const int wv   = tid >> 6;

  // ---- issue async Ws tap-0 staging first; X staging below covers its latency ----
  {
    const unsigned short* s0 = wt + lane * 8;
    #pragma unroll
    for (int j = 0; j < 4; ++j) {
      const int i = wv * 4 + j;
      gload_lds16(s0 + i * 512, &Ws[0][i * 1024]);
    }
  }

  // ---- stage X tile interior (fp32 -> bf16), storage pixel cols 1..32 ----
  {
    const int xi = tid & 31;
    const int cq = tid >> 5;                 // 0..7 -> 4 channels each
    #pragma unroll
    for (int pass = 0; pass < 2; ++pass) {
      const int c0 = pass * 32 + cq * 4;
      const int kg = c0 >> 3;                // k-group row
      const int bo = (c0 & 7) * 2;           // 0 or 8 within the 16B cell
      const float* pbase = xin + ((size_t)img * C_IN + c0) * HW + gx0 + xi;
      #pragma unroll
      for (int r = 0; r < HROWS; ++r) {
        const int gy = gy0 - 1 + r;
        float f0 = 0.f, f1 = 0.f, f2 = 0.f, f3 = 0.f;
        if (gy >= 0 && gy < Himg) {
          const float* p = pbase + (size_t)gy * Wimg;
          f0 = p[0];
          f1 = p[HW];
          f2 = p[2 * HW];
          f3 = p[3 * HW];
        }
        const int pix = r * HCOLS + 1 + xi;
        *(uint2*)(&Xs[kg * XKSTR + pix * 16 + bo]) = make_uint2(pack2(f0, f1), pack2(f2, f3));
      }
    }
  }
  // ---- halo columns (pixel col 0 and 33) ----
  for (int idx = tid; idx < 2 * HROWS * C_IN; idx += 256) {
    const int side = (idx >= HROWS * C_IN) ? 1 : 0;
    const int rem  = idx - side * HROWS * C_IN;
    const int c = rem & 63;
    const int r = rem >> 6;
    const int gy = gy0 - 1 + r;
    const int gx = side ? (gx0 + TCOLS) : (gx0 - 1);
    float f = 0.f;
    if (gy >= 0 && gy < Himg && gx >= 0 && gx < Wimg)
      f = xin[((size_t)img * C_IN + c) * HW + (size_t)gy * Wimg + gx];
    const int pix = r * HCOLS + (side ? (HCOLS - 1) : 0);
    union { __bf16 h; unsigned short s; } u; u.h = (__bf16)f;
    *(unsigned short*)(&Xs[(c >> 3) * XKSTR + pix * 16 + (c & 7) * 2]) = u.s;
  }

  // wave tile: (wm: co-half 64) x (wn: px-half 4 rows of 32)
  const int lpx = lane & 31;
  const int lkh = lane >> 5;
  const int wm  = wv >> 1;
  const int wn  = wv & 1;

  f32x16 acc[2][4];
  #pragma unroll
  for (int mf = 0; mf < 2; ++mf)
    #pragma unroll
    for (int nf = 0; nf < 4; ++nf)
      acc[mf][nf] = (f32x16)(0.f);

  // A cell: Ws[ks*2+lkh][wm*64+mf*32+lpx];  B cell: Xs[ks*2+lkh][pixel]
  const int abase = lkh * 2048 + (wm * 64 + lpx) * 16;   // + mf*512 + ks*4096
  const int xbase = lkh * XKSTR;                          // + ks*2*XKSTR + pix*16

  __syncthreads();   // Xs + Ws[0] ready (syncthreads drains vmcnt)

  for (int t = 0; t < 9; ++t) {
    if (t < 8) {   // async-prefetch tap t+1 (its buffer was last read in tap t-1; barrier-safe)
      const unsigned short* sn = wt + (t + 1) * 8192 + lane * 8;
      unsigned char* db = Ws[(t + 1) & 1];
      #pragma unroll
      for (int j = 0; j < 4; ++j) {
        const int i = wv * 4 + j;
        gload_lds16(sn + i * 512, &db[i * 1024]);
      }
    }
    const int dy = (t >= 6) ? 2 : (t >= 3 ? 1 : 0);
    const int dx = t - dy * 3;
    const unsigned char* wsb = Ws[t & 1];
    int boff[4];
    #pragma unroll
    for (int nf = 0; nf < 4; ++nf)
      boff[nf] = xbase + ((wn * 4 + nf + dy) * HCOLS + dx + lpx) * 16;
    #pragma unroll
    for (int sh = 0; sh < 2; ++sh) {   // k-steps in batches of 2 to bound live regs
      bf16x8 A[2][2], B[4][2];
      #pragma unroll
      for (int ss = 0; ss < 2; ++ss) {
        const int ks = sh * 2 + ss;
        #pragma unroll
        for (int mf = 0; mf < 2; ++mf)
          A[mf][ss] = *(const bf16x8*)&wsb[abase + mf * 512 + ks * 4096];
        #pragma unroll
        for (int nf = 0; nf < 4; ++nf)
          B[nf][ss] = *(const bf16x8*)&Xs[boff[nf] + ks * 2 * XKSTR];
      }
      #pragma unroll
      for (int ss = 0; ss < 2; ++ss)
        #pragma unroll
        for (int mf = 0; mf < 2; ++mf)
          #pragma unroll
          for (int nf = 0; nf < 4; ++nf)
            acc[mf][nf] = __builtin_amdgcn_mfma_f32_32x32x16_bf16(A[mf][ss], B[nf][ss], acc[mf][nf], 0, 0, 0);
    }
    __syncthreads();
  }

  // ---- epilogue: bias + fp32 full-line stores ----
  float4 bq[2][4];
  #pragma unroll
  for (int mf = 0; mf < 2; ++mf)
    #pragma unroll
    for (int rq = 0; rq < 4; ++rq)
      bq[mf][rq] = *(const float4*)(bias + wm * 64 + mf * 32 + rq * 8 + lkh * 4);

  #pragma unroll
  for (int nf = 0; nf < 4; ++nf) {
    const int y = gy0 + wn * 4 + nf;
    float* op = out + (size_t)img * C_OUT * HW + (size_t)y * Wimg + gx0 + lpx;
    #pragma unroll
    for (int mf = 0; mf < 2; ++mf) {
      #pragma unroll
      for (int r = 0; r < 16; ++r) {
        const int co = wm * 64 + mf * 32 + (r & 3) + 8 * (r >> 2) + lkh * 4;
        op[(size_t)co * HW] = acc[mf][nf][r] + ((const float*)&bq[mf][r >> 2])[r & 3];
      }
    }
  }
}

extern "C" void kernel_launch(void* const* d_in, const int* in_sizes, int n_in,
                              void* d_out, int out_size, void* d_ws, size_t ws_size,
                              hipStream_t stream) {
  const float* x    = (const float*)d_in[0];
  const float* w    = (const float*)d_in[1];
  const float* bias = (const float*)d_in[2];
  float* out = (float*)d_out;
  unsigned short* wt = (unsigned short*)d_ws;  // 9*8192 bf16 = 144 KB

  wt_transform<<<(9 * C_OUT * C_IN + 255) / 256, 256, 0, stream>>>(w, wt);

  conv_mfma<<<dim3(2304), 256, 0, stream>>>(x, wt, bias, out);
}